// Round 12
// baseline (481.146 us; speedup 1.0000x reference)
//
#include <hip/hip_runtime.h>
#include <cstdint>
#include <cstddef>

#define D_MODEL 1024
#define SEQ_LEN 4096
#define NBATCH  4
#define M_ROWS  (NBATCH * SEQ_LEN)   // 16384 rows (b*4096+n)
#define NCHUNK  64
#define CHLEN   64                   // SEQ_LEN / NCHUNK
#define GN_EPS_F 0.00064f

typedef unsigned short u16;
typedef __attribute__((ext_vector_type(4))) float f32x4;
typedef __attribute__((ext_vector_type(8))) __bf16 bf16x8;

enum { ACT_DECAY = 0, ACT_TANH, ACT_VMUL, ACT_U, ACT_SIG, ACT_BIAS, ACT_ID };

__device__ __forceinline__ u16 f2bf(float f) {
  union { float f; uint32_t u; } un; un.f = f;
  uint32_t r = (un.u + 0x7FFFu + ((un.u >> 16) & 1u)) >> 16;  // RNE
  return (u16)r;
}
__device__ __forceinline__ float bf2f(u16 h) {
  union { uint32_t u; float f; } un; un.u = ((uint32_t)h) << 16;
  return un.f;
}
__device__ __forceinline__ float sigm(float y) { return 1.f / (1.f + expf(-y)); }

__device__ __forceinline__ void unp8(const uint4 v, float* f) {
  const uint32_t* p = (const uint32_t*)&v;
#pragma unroll
  for (int i = 0; i < 4; i++) {
    f[2 * i]     = bf2f((u16)(p[i] & 0xFFFF));
    f[2 * i + 1] = bf2f((u16)(p[i] >> 16));
  }
}
__device__ __forceinline__ uint4 pck8(const float* f) {
  uint4 v; uint32_t* p = (uint32_t*)&v;
#pragma unroll
  for (int i = 0; i < 4; i++)
    p[i] = (uint32_t)f2bf(f[2 * i]) | ((uint32_t)f2bf(f[2 * i + 1]) << 16);
  return v;
}

// async global->LDS, 16B/lane. LDS dst = wave-uniform base (HW adds lane*16).
__device__ __forceinline__ void load_lds16(const u16* g, u16* l) {
  __builtin_amdgcn_global_load_lds(
      (const __attribute__((address_space(1))) void*)g,
      (__attribute__((address_space(3))) void*)l, 16, 0, 0);
}

// ---------------- weights f32 -> bf16 (7 matrices, contiguous slots) ----------
__global__ __launch_bounds__(256) void wconv(
    const float* __restrict__ w0, const float* __restrict__ w1,
    const float* __restrict__ w2, const float* __restrict__ w3,
    const float* __restrict__ w4, const float* __restrict__ w5,
    const float* __restrict__ w6, u16* __restrict__ Wb) {
  const int gid = blockIdx.x * 256 + threadIdx.x;  // over 7*262144 float4s
  const int m = gid >> 18;
  const int off = gid & 262143;
  const float* src;
  switch (m) {
    case 0: src = w0; break; case 1: src = w1; break; case 2: src = w2; break;
    case 3: src = w3; break; case 4: src = w4; break; case 5: src = w5; break;
    default: src = w6; break;
  }
  const float4 v = ((const float4*)src)[off];
  ushort4 o;
  o.x = f2bf(v.x); o.y = f2bf(v.y); o.z = f2bf(v.z); o.w = f2bf(v.w);
  ((ushort4*)Wb)[gid] = o;
}

// -------- z = x + (prev - x) * mix for TWO mixes in one x pass -> bf16 -------
__global__ __launch_bounds__(256) void zgen2(
    const float* __restrict__ x, const float* __restrict__ mixA,
    const float* __restrict__ mixB, u16* __restrict__ zA,
    u16* __restrict__ zB) {
  const int gid = blockIdx.x * 256 + threadIdx.x;  // over M_ROWS*D/4 = 4,194,304
  const int dv = gid & 255;                        // float4 index within row
  const int n = (gid >> 8) & (SEQ_LEN - 1);
  const float4 xv = ((const float4*)x)[gid];
  float4 pv = make_float4(0.f, 0.f, 0.f, 0.f);
  if (n > 0) pv = ((const float4*)x)[gid - 256];   // previous token, same batch
  const float4 dxv = make_float4(pv.x - xv.x, pv.y - xv.y, pv.z - xv.z, pv.w - xv.w);
  const float4 ma = ((const float4*)mixA)[dv];
  const float4 mb = ((const float4*)mixB)[dv];
  ushort4 oa, ob;
  oa.x = f2bf(xv.x + dxv.x * ma.x); ob.x = f2bf(xv.x + dxv.x * mb.x);
  oa.y = f2bf(xv.y + dxv.y * ma.y); ob.y = f2bf(xv.y + dxv.y * mb.y);
  oa.z = f2bf(xv.z + dxv.z * ma.z); ob.z = f2bf(xv.z + dxv.z * mb.z);
  oa.w = f2bf(xv.w + dxv.w * ma.w); ob.w = f2bf(xv.w + dxv.w * mb.w);
  ((ushort4*)zA)[gid] = oa;
  ((ushort4*)zB)[gid] = ob;
}

// ---------------- bf16 GEMM: out = A @ W^T -----------------------------------
// 128x256 tile, BK=32, 8 waves (2Mx4N), 512 thr, LDS 48KB -> 2 blocks/CU.
// Fully unrolled K-loop: buffer index compile-time, LDS read offsets hoisted
// to registers (ds_read offset: immediate carries the buffer base), staging
// offsets fold to literals. Counted vmcnt(2), raw s_barrier, setprio,
// 2-way-free swizzle (chunk ^= (row>>1)&3), XCD-chunked grid.
template <int ACT>
__global__ __launch_bounds__(512, 4) void gemm_bt(
    const u16* __restrict__ A,   // [M][1024] bf16
    const u16* __restrict__ Bw,  // [1024][1024] bf16 row-major (torch W)
    void* __restrict__ outp,
    const u16* __restrict__ aux,     // kv for ACT_U, k for ACT_VMUL
    const float* __restrict__ bias) {  // for ACT_BIAS
  __shared__ __align__(16) u16 AL[2][128 * 32];   // 8 KB each
  __shared__ __align__(16) u16 BL[2][256 * 32];   // 16 KB each
  const int tid = threadIdx.x;
  const int lane = tid & 63;
  const int wid = tid >> 6;
  const int wr = wid >> 2;           // 0..1  (M half, 64 rows)
  const int wc = wid & 3;            // 0..3  (N quarter, 64 cols)
  const int lr = lane & 15;
  const int lk = lane >> 4;

  // XCD-chunked swizzle: 512 blocks, 8 XCDs, 64 contiguous logical tiles each
  const int bid = blockIdx.x;
  const int wgid = (bid & 7) * 64 + (bid >> 3);
  const int m0 = (wgid >> 2) * 128;
  const int n0 = (wgid & 3) * 256;

  // staging: thread t -> row t>>2 (0..127), 16B-chunk (t&3) ^ ((row>>1)&3)
  const int srow = tid >> 2;
  const int ssw  = ((tid & 3) ^ ((srow >> 1) & 3)) * 8;   // u16 col offset
  const u16* gA  = A  + (size_t)(m0 + srow) * D_MODEL + ssw;
  const u16* gB0 = Bw + (size_t)(n0 + srow) * D_MODEL + ssw;
  const u16* gB1 = Bw + (size_t)(n0 + 128 + srow) * D_MODEL + ssw;
#define SA(bufi, kt) load_lds16(gA  + (kt), &AL[bufi][wid * 512])
#define SB0(bufi, kt) load_lds16(gB0 + (kt), &BL[bufi][wid * 512])
#define SB1(bufi, kt) load_lds16(gB1 + (kt), &BL[bufi][4096 + wid * 512])

  // hoisted LDS byte offsets (buffer-independent; base picked by immediate)
  int aoff[4], boff[4];
#pragma unroll
  for (int mi = 0; mi < 4; ++mi) {
    const int R = wr * 64 + mi * 16 + lr;
    aoff[mi] = (R * 32 + ((lk ^ ((R >> 1) & 3)) << 3)) * 2;
  }
#pragma unroll
  for (int nj = 0; nj < 4; ++nj) {
    const int R = wc * 64 + nj * 16 + lr;
    boff[nj] = (R * 32 + ((lk ^ ((R >> 1) & 3)) << 3)) * 2;
  }

  f32x4 acc[4][4];
  const f32x4 z4 = {0.f, 0.f, 0.f, 0.f};
#pragma unroll
  for (int i = 0; i < 4; i++)
#pragma unroll
    for (int j = 0; j < 4; j++) acc[i][j] = z4;

  // prologue: tile 0 into buf 0
  SB0(0, 0); SB1(0, 0); SA(0, 0);

#pragma unroll
  for (int t = 0; t < 32; ++t) {
    const int cb = t & 1;            // compile-time after full unroll
    const int nb = cb ^ 1;
    const int ktn = (t + 1) * 32;    // literal after unroll
    bf16x8 a[4], b[4];

    // ---- P1: issue next B; counted wait; read all frags; MFMA nj 0..1
    if (t < 31) {
      SB0(nb, ktn); SB1(nb, ktn);
      asm volatile("s_waitcnt vmcnt(2)" ::: "memory");
    } else {
      asm volatile("s_waitcnt vmcnt(0)" ::: "memory");
    }
    __builtin_amdgcn_s_barrier();
    __builtin_amdgcn_sched_barrier(0);   // no ds_read hoists above the barrier
#pragma unroll
    for (int mi = 0; mi < 4; ++mi)
      a[mi] = *(const bf16x8*)((const char*)&AL[cb][0] + aoff[mi]);
#pragma unroll
    for (int nj = 0; nj < 4; ++nj)
      b[nj] = *(const bf16x8*)((const char*)&BL[cb][0] + boff[nj]);
    __builtin_amdgcn_s_setprio(1);
#pragma unroll
    for (int mi = 0; mi < 4; ++mi)
#pragma unroll
      for (int nj = 0; nj < 2; ++nj)
        acc[mi][nj] = __builtin_amdgcn_mfma_f32_16x16x32_bf16(a[mi], b[nj], acc[mi][nj], 0, 0, 0);
    __builtin_amdgcn_s_setprio(0);

    // ---- P2: issue next A; MFMA nj 2..3
    if (t < 31) SA(nb, ktn);
    __builtin_amdgcn_s_barrier();
    __builtin_amdgcn_s_setprio(1);
#pragma unroll
    for (int mi = 0; mi < 4; ++mi)
#pragma unroll
      for (int nj = 2; nj < 4; ++nj)
        acc[mi][nj] = __builtin_amdgcn_mfma_f32_16x16x32_bf16(a[mi], b[nj], acc[mi][nj], 0, 0, 0);
    __builtin_amdgcn_s_setprio(0);
  }
#undef SA
#undef SB0
#undef SB1

  // epilogue; C/D layout: col = lane&15, row = (lane>>4)*4 + e  [m89-verified]
#pragma unroll
  for (int mi = 0; mi < 4; ++mi) {
#pragma unroll
    for (int nj = 0; nj < 4; ++nj) {
#pragma unroll
      for (int e = 0; e < 4; ++e) {
        const int row = m0 + wr * 64 + mi * 16 + lk * 4 + e;
        const int col = n0 + wc * 64 + nj * 16 + lr;
        const size_t idx = (size_t)row * D_MODEL + col;
        const float y = acc[mi][nj][e];
        if constexpr (ACT == ACT_ID) {
          ((u16*)outp)[idx] = f2bf(y);                           // raw lin (w)
        } else if constexpr (ACT == ACT_TANH) {
          ((u16*)outp)[idx] = f2bf(tanhf(y));
        } else if constexpr (ACT == ACT_VMUL) {
          ((u16*)outp)[idx] = f2bf(y * bf2f(aux[idx]));          // kv = v * k
        } else if constexpr (ACT == ACT_U) {
          ((u16*)outp)[idx] = f2bf(sigm(y) * bf2f(aux[idx]));    // u = alpha * kv
        } else if constexpr (ACT == ACT_SIG) {
          ((u16*)outp)[idx] = f2bf(sigm(y));
        } else {  // ACT_BIAS
          ((float*)outp)[idx] = y + bias[col];
        }
      }
    }
  }
}

// ------- chunked scan, scalar 1 ch/thread (R7-verified: TLP-bound regime) ----
__global__ __launch_bounds__(256) void scan1(
    const u16* __restrict__ wraw, const u16* __restrict__ u,
    float* __restrict__ Ac, float* __restrict__ Sc) {
  const int gid = blockIdx.x * 256 + threadIdx.x;  // c*4096 + b*1024 + d
  const int d = gid & 1023;
  const int b = (gid >> 10) & 3;
  const int c = gid >> 12;
  const size_t base = ((size_t)b * SEQ_LEN + (size_t)c * CHLEN) * D_MODEL + d;
  float A = 1.f, S = 0.f;
#pragma unroll 4
  for (int t = 0; t < CHLEN; t++) {
    const size_t off = base + (size_t)t * D_MODEL;
    const float dd = 1.f / (1.f + expf(bf2f(wraw[off])));  // sigmoid(-y)
    S = S * dd + bf2f(u[off]);
    A *= dd;
  }
  Ac[gid] = A;
  Sc[gid] = S;
}

__global__ __launch_bounds__(256) void scan2(
    const float* __restrict__ Ac, const float* __restrict__ Sc,
    float* __restrict__ In) {
  const int gid = blockIdx.x * 256 + threadIdx.x;  // b*1024 + d, 4096 total
  float carry = 0.f;
#pragma unroll 4
  for (int c = 0; c < NCHUNK; c++) {
    const int i = c * 4096 + gid;
    In[i] = carry;
    carry = carry * Ac[i] + Sc[i];
  }
}

__global__ __launch_bounds__(256) void scan3(
    const u16* __restrict__ wraw, const u16* __restrict__ u,
    const u16* __restrict__ r, const float* __restrict__ In,
    u16* __restrict__ mixed) {
  const int gid = blockIdx.x * 256 + threadIdx.x;
  const int d = gid & 1023;
  const int b = (gid >> 10) & 3;
  const int c = gid >> 12;
  const size_t base = ((size_t)b * SEQ_LEN + (size_t)c * CHLEN) * D_MODEL + d;
  float state = In[gid];
#pragma unroll 4
  for (int t = 0; t < CHLEN; t++) {
    const size_t off = base + (size_t)t * D_MODEL;
    const float dd = 1.f / (1.f + expf(bf2f(wraw[off])));  // sigmoid(-y)
    state = state * dd + bf2f(u[off]);
    mixed[off] = f2bf(bf2f(r[off]) * state);
  }
}

// ------- GroupNorm(H=16, 64ch) * g -> bf16; 8 ch/thread, 8-lane subgroup ----
__global__ __launch_bounds__(256) void gnorm(
    const u16* __restrict__ mixed, const u16* __restrict__ g,
    const float* __restrict__ gw, const float* __restrict__ gb,
    u16* __restrict__ h) {
  const int G = blockIdx.x * 32 + (threadIdx.x >> 3);  // group id, 262144 total
  const int sub = threadIdx.x & 7;
  const int row = G >> 4;
  const int hh = G & 15;
  const int d0 = hh * 64 + sub * 8;
  const size_t i4 = ((size_t)row * D_MODEL + d0) >> 3;  // uint4 units
  float mv[8], gv[8];
  unp8(((const uint4*)mixed)[i4], mv);
  unp8(((const uint4*)g)[i4], gv);
  float s = 0.f, s2 = 0.f;
#pragma unroll
  for (int i = 0; i < 8; i++) { s += mv[i]; s2 += mv[i] * mv[i]; }
#pragma unroll
  for (int m = 1; m < 8; m <<= 1) {   // within 8-lane subgroup
    s += __shfl_xor(s, m, 64);
    s2 += __shfl_xor(s2, m, 64);
  }
  const float mu = s * (1.f / 64.f);
  const float var = s2 * (1.f / 64.f) - mu * mu;
  const float inv = 1.f / sqrtf(var + GN_EPS_F);
  const float4 gw0 = ((const float4*)gw)[d0 >> 2], gw1 = ((const float4*)gw)[(d0 >> 2) + 1];
  const float4 gb0 = ((const float4*)gb)[d0 >> 2], gb1 = ((const float4*)gb)[(d0 >> 2) + 1];
  const float W[8] = {gw0.x, gw0.y, gw0.z, gw0.w, gw1.x, gw1.y, gw1.z, gw1.w};
  const float Bb[8] = {gb0.x, gb0.y, gb0.z, gb0.w, gb1.x, gb1.y, gb1.z, gb1.w};
  float ov[8];
#pragma unroll
  for (int i = 0; i < 8; i++)
    ov[i] = ((mv[i] - mu) * inv * W[i] + Bb[i]) * gv[i];
  ((uint4*)h)[i4] = pck8(ov);
}

// ---------------- host ---------------------------------------------------------
extern "C" void kernel_launch(void* const* d_in, const int* in_sizes, int n_in,
                              void* d_out, int out_size, void* d_ws, size_t ws_size,
                              hipStream_t stream) {
  (void)in_sizes; (void)n_in; (void)out_size; (void)ws_size;
  const float* x    = (const float*)d_in[0];
  const float* mx_r = (const float*)d_in[1];
  const float* mx_w = (const float*)d_in[2];
  const float* mx_k = (const float*)d_in[3];
  const float* mx_v = (const float*)d_in[4];
  const float* mx_a = (const float*)d_in[5];
  const float* mx_g = (const float*)d_in[6];
  const float* W_r  = (const float*)d_in[7];
  const float* W_w  = (const float*)d_in[8];
  const float* W_k  = (const float*)d_in[9];
  const float* W_v  = (const float*)d_in[10];
  const float* W_a  = (const float*)d_in[11];
  const float* W_g  = (const float*)d_in[12];
  const float* W_o  = (const float*)d_in[13];
  const float* b_out = (const float*)d_in[14];
  const float* gn_w  = (const float*)d_in[15];
  const float* gn_b  = (const float*)d_in[16];

  // Workspace plan (209 MB; all bf16 intermediates):
  //   0: Wb 14 | 14: Ac 1 | 15: Sc 1 | 16: z1 32 (z_w/z_v/z_r; later mixed)
  //   48: z2 32 (z_k/z_a/z_g; later h) | 80: wraw 32 | 112: ubuf 32
  //   144: kbuf 32 (k; later r) | 176: vbuf 32 (kv; later g) | 208: In 1
  char* ws = (char*)d_ws;
  const size_t MB = 1024ull * 1024ull;
  u16*   Wb   = (u16*)(ws);
  float* Ac   = (float*)(ws + 14 * MB);
  float* Sc   = (float*)(ws + 15 * MB);
  u16*   z1   = (u16*)(ws + 16 * MB);
  u16*   z2   = (u16*)(ws + 48 * MB);
  u16*   wraw = (u16*)(ws + 80 * MB);
  u16*   ubuf = (u16*)(ws + 112 * MB);
  u16*   kbuf = (u16*)(ws + 144 * MB);
  u16*   vbuf = (u16*)(ws + 176 * MB);
  float* Inb  = (float*)(ws + 208 * MB);

  wconv<<<7168, 256, 0, stream>>>(W_r, W_w, W_k, W_v, W_a, W_g, W_o, Wb);

  // pair 1: z_w, z_k
  zgen2<<<16384, 256, 0, stream>>>(x, mx_w, mx_k, z1, z2);
  gemm_bt<ACT_ID><<<512, 512, 0, stream>>>(z1, Wb + 1 * 1048576, wraw, nullptr, nullptr);
  gemm_bt<ACT_TANH><<<512, 512, 0, stream>>>(z2, Wb + 2 * 1048576, kbuf, nullptr, nullptr);
  // pair 2: z_v, z_a
  zgen2<<<16384, 256, 0, stream>>>(x, mx_v, mx_a, z1, z2);
  gemm_bt<ACT_VMUL><<<512, 512, 0, stream>>>(z1, Wb + 3 * 1048576, vbuf, kbuf, nullptr);
  gemm_bt<ACT_U><<<512, 512, 0, stream>>>(z2, Wb + 4 * 1048576, ubuf, vbuf, nullptr);
  // pair 3: z_r, z_g
  zgen2<<<16384, 256, 0, stream>>>(x, mx_r, mx_g, z1, z2);
  gemm_bt<ACT_SIG><<<512, 512, 0, stream>>>(z1, Wb + 0, kbuf, nullptr, nullptr);
  gemm_bt<ACT_SIG><<<512, 512, 0, stream>>>(z2, Wb + 5 * 1048576, vbuf, nullptr, nullptr);

  // recurrence (chunked parallel scan); mixed (bf16) -> z1
  scan1<<<1024, 256, 0, stream>>>(wraw, ubuf, Ac, Sc);
  scan2<<<16, 256, 0, stream>>>(Ac, Sc, Inb);
  scan3<<<1024, 256, 0, stream>>>(wraw, ubuf, kbuf, Inb, z1);

  // groupnorm(mixed) * g -> h (bf16, into z2)
  gnorm<<<8192, 256, 0, stream>>>(z1, vbuf, gn_w, gn_b, z2);

  // out = h @ W_out^T + b_out, f32
  gemm_bt<ACT_BIAS><<<512, 512, 0, stream>>>(z2, Wb + 6 * 1048576, (float*)d_out, nullptr, b_out);
}